// Round 1
// 526.936 us; speedup vs baseline: 1.1182x; 1.1182x over previous
//
#include <hip/hip_runtime.h>
#include <hip/hip_bf16.h>
#include <stdint.h>

// ConvDecoderLayer: B=8, T=S=2048, D=512, K=3
// out = (LN2(h + (attn@v)@Wo^T + bo), attn), h = LN1(GLU(causal_conv(x)) + x)

typedef unsigned short ushortT;
typedef __bf16 bf16x8 __attribute__((ext_vector_type(8)));
typedef float floatx4 __attribute__((ext_vector_type(4)));
typedef unsigned short ushort4v __attribute__((ext_vector_type(4)));
typedef unsigned short ushort8 __attribute__((ext_vector_type(8)));

__device__ __forceinline__ ushortT f2bf(float f) {
  unsigned u = __builtin_bit_cast(unsigned, f);
  u += 0x7FFFu + ((u >> 16) & 1u);   // RNE
  return (ushortT)(u >> 16);
}
__device__ __forceinline__ float bf2f(ushortT u) {
  return __builtin_bit_cast(float, (unsigned)u << 16);
}

__device__ __forceinline__ void gload_lds16(const void* g, void* l) {
  __builtin_amdgcn_global_load_lds(
      (const __attribute__((address_space(1))) void*)g,
      (__attribute__((address_space(3))) void*)l, 16, 0, 0);
}

// ---------------- conversion kernels ----------------
__global__ __launch_bounds__(256)
void k_f32_to_bf16v(const float* __restrict__ src, ushortT* __restrict__ dst, long n4) {
  long i = (long)blockIdx.x * 256 + threadIdx.x;
  if (i >= n4) return;
  floatx4 v = *(const floatx4*)&src[i * 4];
  ushort4v o;
#pragma unroll
  for (int j = 0; j < 4; j++) o[j] = f2bf(v[j]);
  *(ushort4v*)&dst[i * 4] = o;
}

// four 512x512 weights -> bf16, one launch
__global__ __launch_bounds__(256)
void k_w4(const float* __restrict__ w0, const float* __restrict__ w1,
          const float* __restrict__ w2, const float* __restrict__ w3,
          ushortT* __restrict__ dst) {
  long i = (long)blockIdx.x * 256 + threadIdx.x;   // float4 groups, 4*65536 total
  int m = (int)(i >> 16);
  long within = (i & 65535) * 4;
  const float* s = (m == 0) ? w0 : (m == 1) ? w1 : (m == 2) ? w2 : w3;
  floatx4 v = *(const floatx4*)&s[within];
  ushort4v o;
#pragma unroll
  for (int j = 0; j < 4; j++) o[j] = f2bf(v[j]);
  *(ushort4v*)&dst[(long)m * 262144 + within] = o;
}

// x [8,2048,512] f32 -> xpad [8,2050,512] bf16 with 2 leading zero rows per batch
__global__ __launch_bounds__(128)
void k_xpad(const float* __restrict__ x, ushortT* __restrict__ xp) {
  int row = blockIdx.x;                 // 8*2050
  int b = row / 2050, tp = row % 2050;
  int c = threadIdx.x * 4;
  ushort4v o = {0, 0, 0, 0};
  if (tp >= 2) {
    floatx4 v = *(const floatx4*)&x[((long)(b * 2048 + tp - 2)) * 512 + c];
#pragma unroll
    for (int j = 0; j < 4; j++) o[j] = f2bf(v[j]);
  }
  *(ushort4v*)&xp[(long)row * 512 + c] = o;
}

// conv_w [1024][512][3] -> interleaved B^T form Wc'[n][kk], kk = tap*512+i
__global__ __launch_bounds__(256)
void k_convw(const float* __restrict__ w, ushortT* __restrict__ dst) {
  long idx = (long)blockIdx.x * 256 + threadIdx.x;
  if (idx >= 1024L * 1536) return;
  int n = (int)(idx / 1536), kk = (int)(idx % 1536);
  int tap = kk >> 9, i = kk & 511;
  int o = ((n >> 4) & 1) * 512 + (n >> 5) * 16 + (n & 15);
  dst[idx] = f2bf(w[(o * 512 + i) * 3 + tap]);
}

// ---------------- 128x128 GEMM (legacy, used for vT only) ----------------
template<int CONV_A, int BIAS, int GLU, int WBF16, int SWAP = 0>
__global__ __launch_bounds__(256)
void k_gemm(const ushortT* __restrict__ A, long aBatch, int lda,
            const ushortT* __restrict__ Bm, long bBatch, int ldb,
            const float* __restrict__ bias, const float* __restrict__ xres,
            float* __restrict__ Cf, ushortT* __restrict__ Cb, long cBatch, int ldc,
            int Kdim, float scale)
{
  __shared__ ushortT As[128 * 32];
  __shared__ ushortT Bs[128 * 32];
  const int tid  = threadIdx.x;
  const int lane = tid & 63;
  const int wave = tid >> 6;
  const int wrow = (wave >> 1) * 64;
  const int wcol = (wave & 1) * 64;
  const int l15  = lane & 15;
  const int quad = lane >> 4;
  const long zA = (long)blockIdx.z * aBatch;
  const long zB = (long)blockIdx.z * bBatch;
  const long zC = (long)blockIdx.z * cBatch;
  const int rowBase = (SWAP ? blockIdx.y : blockIdx.x) * 128;
  const int colBase = (SWAP ? blockIdx.x : blockIdx.y) * 128;

  floatx4 zero = {0.f, 0.f, 0.f, 0.f};
  floatx4 acc[4][4];
#pragma unroll
  for (int mi = 0; mi < 4; mi++)
#pragma unroll
    for (int ni = 0; ni < 4; ni++) acc[mi][ni] = zero;

  for (int k0 = 0; k0 < Kdim; k0 += 32) {
    __syncthreads();
    {
      int ch = tid;
#pragma unroll
      for (int it = 0; it < 2; it++, ch += 256) {
        int row = ch >> 2, c8 = (ch & 3) << 3;
        if (CONV_A) {
          int gr = rowBase + row, gc = k0 + c8;
          int tap = gc >> 9, ii = gc & 511;
          int b = gr >> 11, t = gr & 2047;
          long gofs = ((long)(b * 2050 + t + tap) << 9) + ii;
          gload_lds16(A + gofs, &As[ch * 8]);
        } else {
          long gofs = zA + (long)(rowBase + row) * lda + (k0 + c8);
          gload_lds16(A + gofs, &As[ch * 8]);
        }
      }
      ch = tid;
#pragma unroll
      for (int it = 0; it < 2; it++, ch += 256) {
        int row = ch >> 2, c8 = (ch & 3) << 3;
        long gofs = zB + (long)(colBase + row) * ldb + (k0 + c8);
        gload_lds16(Bm + gofs, &Bs[ch * 8]);
      }
    }
    __syncthreads();
    bf16x8 av[4], bv[4];
#pragma unroll
    for (int mi = 0; mi < 4; mi++)
      av[mi] = *(const bf16x8*)&As[(wrow + mi * 16 + l15) * 32 + quad * 8];
#pragma unroll
    for (int ni = 0; ni < 4; ni++)
      bv[ni] = *(const bf16x8*)&Bs[(wcol + ni * 16 + l15) * 32 + quad * 8];
#pragma unroll
    for (int mi = 0; mi < 4; mi++)
#pragma unroll
      for (int ni = 0; ni < 4; ni++)
        acc[mi][ni] = __builtin_amdgcn_mfma_f32_16x16x32_bf16(av[mi], bv[ni], acc[mi][ni], 0, 0, 0);
  }

  if (GLU) {
#pragma unroll
    for (int mi = 0; mi < 4; mi++) {
#pragma unroll
      for (int ni = 0; ni < 4; ni += 2) {
        int colA = colBase + wcol + ni * 16;
        int d = (colA >> 5) * 16 + l15;
        float ba = bias[d], bg = bias[512 + d];
#pragma unroll
        for (int r = 0; r < 4; r++) {
          int grow = rowBase + wrow + mi * 16 + quad * 4 + r;
          float a = acc[mi][ni][r] + ba;
          float g = acc[mi][ni + 1][r] + bg;
          float val = a / (1.0f + __expf(-g)) + xres[(long)grow * 512 + d];
          Cf[(long)grow * 512 + d] = val;
        }
      }
    }
  } else {
#pragma unroll
    for (int mi = 0; mi < 4; mi++) {
#pragma unroll
      for (int ni = 0; ni < 4; ni++) {
        int gcol = colBase + wcol + ni * 16 + l15;
        float bcol = (BIAS == 1) ? bias[gcol] : 0.0f;
#pragma unroll
        for (int r = 0; r < 4; r++) {
          int grow = rowBase + wrow + mi * 16 + quad * 4 + r;
          float val = acc[mi][ni][r] * scale + bcol + ((BIAS == 2) ? bias[grow] : 0.0f);
          long off = zC + (long)grow * ldc + gcol;
          if (WBF16) Cb[off] = f2bf(val);
          else       Cf[off] = val;
        }
      }
    }
  }
}

// ---------------- 256x256 counted-vmcnt double-buffered GEMM ----------------
// 8 waves (2M x 4N), BK=64, 128 KiB LDS (2 buffers x (A 32K + B 32K)).
// Schedule per K-tile t: s_waitcnt vmcnt(8) -> s_barrier -> ds_read+MFMA (no
// inner barriers, reads only) -> s_barrier -> issue tile t+2's 8 global_load_lds.
// Prefetch depth 2; vmcnt never drained to 0 in the main loop (T3+T4).
// LDS XOR-swizzle (T2): 16B chunk index c stored at slot c^(row&7); LDS dest
// stays linear (global_load_lds requirement), the GLOBAL source is pre-swizzled
// and the ds_read applies the same involution.
template<int CONV_A, int GLU, int BIAS, int WBF16, int DUALZ, int SWAP>
__global__ __launch_bounds__(512)
void k_gemm256(const ushortT* __restrict__ A, const ushortT* __restrict__ A2, int lda, long aBatch,
               const ushortT* __restrict__ Bm, const ushortT* __restrict__ Bm2, int ldb, long bBatch,
               const float* __restrict__ bias, const float* __restrict__ bias2,
               const float* __restrict__ xres,
               float* __restrict__ Cf, ushortT* __restrict__ Cb, ushortT* __restrict__ Cb2,
               long cBatch, int ldc, int Kdim, float scale)
{
  __shared__ ushortT lds[2][2 * 16384];   // [buf][A(16384) | B(16384)] = 128 KiB

  const int tid  = threadIdx.x;           // 0..511
  const int lane = tid & 63;
  const int wave = tid >> 6;              // 0..7
  const int wr   = wave >> 2;             // 0..1  (M)
  const int wc   = wave & 3;              // 0..3  (N)
  const int l15  = lane & 15;
  const int quad = lane >> 4;

  const ushortT* Ap = A;
  const ushortT* Bp = Bm;
  const float* biasP = bias;
  ushortT* CbP = Cb;
  if (DUALZ && blockIdx.z) { Ap = A2; Bp = Bm2; biasP = bias2; CbP = Cb2; }
  const long zA = DUALZ ? 0 : (long)blockIdx.z * aBatch;
  const long zB = DUALZ ? 0 : (long)blockIdx.z * bBatch;
  const long zC = DUALZ ? 0 : (long)blockIdx.z * cBatch;
  const int rowBase = (SWAP ? blockIdx.y : blockIdx.x) * 256;
  const int colBase = (SWAP ? blockIdx.x : blockIdx.y) * 256;

  // stage one K-tile (A 256x64 + B 256x64 bf16) into buf[t&1]; 8 loads/thread-less:
  // 4 A-loads + 4 B-loads of 16B per thread, LDS dest linear (wave-uniform+lane*16).
  auto STAGE = [&](int t) {
    ushortT* sA = lds[t & 1];
    ushortT* sB = sA + 16384;
    const int k0 = t << 6;
#pragma unroll
    for (int l = 0; l < 4; l++) {
      int idx = l * 512 + tid;            // 0..2047
      int row = idx >> 3;                 // 0..255
      int ck  = ((tid & 7) ^ (row & 7)) << 3;  // swizzled element col within BK
      if (CONV_A) {
        int gr = rowBase + row;
        int gc = k0 + ck;
        int tap = gc >> 9, ii = gc & 511;
        int b = gr >> 11, tt = gr & 2047;
        long gofs = ((long)(b * 2050 + tt + tap) << 9) + ii;
        gload_lds16(Ap + gofs, sA + idx * 8);
      } else {
        long gofs = zA + (long)(rowBase + row) * lda + (k0 + ck);
        gload_lds16(Ap + gofs, sA + idx * 8);
      }
    }
#pragma unroll
    for (int l = 0; l < 4; l++) {
      int idx = l * 512 + tid;
      int row = idx >> 3;
      int ck  = ((tid & 7) ^ (row & 7)) << 3;
      long gofs = zB + (long)(colBase + row) * ldb + (k0 + ck);
      gload_lds16(Bp + gofs, sB + idx * 8);
    }
  };

  // swizzled fragment read: row r, chunk c (= ks*4+quad), 16B
  auto LD = [&](const ushortT* s, int r, int c) -> bf16x8 {
    return *(const bf16x8*)&s[r * 64 + ((c ^ (r & 7)) << 3)];
  };

  floatx4 zero = {0.f, 0.f, 0.f, 0.f};
  floatx4 acc[8][4];
#pragma unroll
  for (int mi = 0; mi < 8; mi++)
#pragma unroll
    for (int ni = 0; ni < 4; ni++) acc[mi][ni] = zero;

  const int NT = Kdim >> 6;
  STAGE(0);
  STAGE(1);

  for (int t = 0; t < NT; t++) {
    if (t < NT - 1) asm volatile("s_waitcnt vmcnt(8)" ::: "memory");
    else            asm volatile("s_waitcnt vmcnt(0)" ::: "memory");
    __builtin_amdgcn_s_barrier();

    const ushortT* sA = lds[t & 1];
    const ushortT* sB = sA + 16384;

    bf16x8 av[4][2], bv[4][2];
#pragma unroll
    for (int ni = 0; ni < 4; ni++)
#pragma unroll
      for (int ks = 0; ks < 2; ks++)
        bv[ni][ks] = LD(sB, wc * 64 + ni * 16 + l15, ks * 4 + quad);
#pragma unroll
    for (int mi = 0; mi < 4; mi++)
#pragma unroll
      for (int ks = 0; ks < 2; ks++)
        av[mi][ks] = LD(sA, wr * 128 + mi * 16 + l15, ks * 4 + quad);

    __builtin_amdgcn_s_setprio(1);
#pragma unroll
    for (int mi = 0; mi < 4; mi++)
#pragma unroll
      for (int ni = 0; ni < 4; ni++)
#pragma unroll
        for (int ks = 0; ks < 2; ks++)
          acc[mi][ni] = __builtin_amdgcn_mfma_f32_16x16x32_bf16(av[mi][ks], bv[ni][ks], acc[mi][ni], 0, 0, 0);
    __builtin_amdgcn_s_setprio(0);

#pragma unroll
    for (int mi = 0; mi < 4; mi++)
#pragma unroll
      for (int ks = 0; ks < 2; ks++)
        av[mi][ks] = LD(sA, wr * 128 + 64 + mi * 16 + l15, ks * 4 + quad);

    __builtin_amdgcn_s_setprio(1);
#pragma unroll
    for (int mi = 0; mi < 4; mi++)
#pragma unroll
      for (int ni = 0; ni < 4; ni++)
#pragma unroll
        for (int ks = 0; ks < 2; ks++)
          acc[4 + mi][ni] = __builtin_amdgcn_mfma_f32_16x16x32_bf16(av[mi][ks], bv[ni][ks], acc[4 + mi][ni], 0, 0, 0);
    __builtin_amdgcn_s_setprio(0);

    __builtin_amdgcn_s_barrier();
    if (t + 2 < NT) STAGE(t + 2);
  }

  if (GLU) {
#pragma unroll
    for (int mi = 0; mi < 8; mi++) {
#pragma unroll
      for (int ni = 0; ni < 4; ni += 2) {
        int colA = colBase + wc * 64 + ni * 16;
        int d = (colA >> 5) * 16 + l15;
        float ba = biasP[d], bg = biasP[512 + d];
#pragma unroll
        for (int r = 0; r < 4; r++) {
          int grow = rowBase + wr * 128 + mi * 16 + quad * 4 + r;
          float a = acc[mi][ni][r] + ba;
          float g = acc[mi][ni + 1][r] + bg;
          float val = a / (1.0f + __expf(-g)) + xres[(long)grow * 512 + d];
          Cf[(long)grow * 512 + d] = val;
        }
      }
    }
  } else {
#pragma unroll
    for (int mi = 0; mi < 8; mi++) {
#pragma unroll
      for (int ni = 0; ni < 4; ni++) {
        int gcol = colBase + wc * 64 + ni * 16 + l15;
        float bcol = BIAS ? biasP[gcol] : 0.0f;
#pragma unroll
        for (int r = 0; r < 4; r++) {
          int grow = rowBase + wr * 128 + mi * 16 + quad * 4 + r;
          float val = acc[mi][ni][r] * scale + bcol;
          long off = zC + (long)grow * ldc + gcol;
          if (WBF16) CbP[off] = f2bf(val);
          else       Cf[off] = val;
        }
      }
    }
  }
}

// ---------------- LN1 -> bf16 only ----------------
__global__ __launch_bounds__(128)
void k_ln(const float* __restrict__ src, const float* __restrict__ w, const float* __restrict__ b,
          ushortT* __restrict__ outb)
{
  __shared__ float s1[2], s2[2];
  long r = blockIdx.x;
  int tid = threadIdx.x;
  floatx4 v = *(const floatx4*)&src[r * 512 + tid * 4];
  float sum = v[0] + v[1] + v[2] + v[3];
  float ssq = v[0]*v[0] + v[1]*v[1] + v[2]*v[2] + v[3]*v[3];
#pragma unroll
  for (int off = 32; off; off >>= 1) { sum += __shfl_xor(sum, off); ssq += __shfl_xor(ssq, off); }
  if ((tid & 63) == 0) { s1[tid >> 6] = sum; s2[tid >> 6] = ssq; }
  __syncthreads();
  sum = s1[0] + s1[1]; ssq = s2[0] + s2[1];
  float mu = sum * (1.0f / 512.0f);
  float var = ssq * (1.0f / 512.0f) - mu * mu;
  float rstd = rsqrtf(var + 1e-5f);
  floatx4 wv = *(const floatx4*)&w[tid * 4];
  floatx4 bv = *(const floatx4*)&b[tid * 4];
  ushort4v ob;
#pragma unroll
  for (int j = 0; j < 4; j++) ob[j] = f2bf((v[j] - mu) * rstd * wv[j] + bv[j]);
  *(ushort4v*)&outb[r * 512 + tid * 4] = ob;
}

// ---------------- softmax: bf16 logits -> fp32 attn (d_out) + bf16 P in place ----------------
__global__ __launch_bounds__(256)
void k_softmax(ushortT* __restrict__ logits, float* __restrict__ attn)
{
  __shared__ float sred[4];
  long r = blockIdx.x;
  ushortT* lrow = logits + r * 2048;
  float* arow = attn + r * 2048;
  int tid = threadIdx.x;
  ushort8 uv = *(const ushort8*)&lrow[tid * 8];
  float v[8];
#pragma unroll
  for (int j = 0; j < 8; j++) v[j] = bf2f(uv[j]);
  float mx = v[0];
#pragma unroll
  for (int j = 1; j < 8; j++) mx = fmaxf(mx, v[j]);
#pragma unroll
  for (int off = 32; off; off >>= 1) mx = fmaxf(mx, __shfl_xor(mx, off));
  if ((tid & 63) == 0) sred[tid >> 6] = mx;
  __syncthreads();
  mx = fmaxf(fmaxf(sred[0], sred[1]), fmaxf(sred[2], sred[3]));
  __syncthreads();
  float sum = 0.f;
#pragma unroll
  for (int j = 0; j < 8; j++) { v[j] = __expf(v[j] - mx); sum += v[j]; }
#pragma unroll
  for (int off = 32; off; off >>= 1) sum += __shfl_xor(sum, off);
  if ((tid & 63) == 0) sred[tid >> 6] = sum;
  __syncthreads();
  sum = sred[0] + sred[1] + sred[2] + sred[3];
  float inv = 1.0f / sum;
  floatx4 o0, o1;
  ushort8 ob;
#pragma unroll
  for (int j = 0; j < 8; j++) {
    float p = v[j] * inv;
    if (j < 4) o0[j] = p; else o1[j - 4] = p;
    ob[j] = f2bf(p);
  }
  *(floatx4*)&arow[tid * 8] = o0;
  *(floatx4*)&arow[tid * 8 + 4] = o1;
  *(ushort8*)&lrow[tid * 8] = ob;
}

// ---------------- fused out-proj + residual + LN2 ----------------
// 32 rows x 512 cols per block; wave w owns cols [128w, 128w+128)
__global__ __launch_bounds__(256)
void k_oproj_ln(const ushortT* __restrict__ ctx, const ushortT* __restrict__ Wo,
                const float* __restrict__ bo, const ushortT* __restrict__ h,
                const float* __restrict__ w, const float* __restrict__ b,
                float* __restrict__ out)
{
  __shared__ ushortT As[32 * 32];
  __shared__ ushortT Bs[512 * 32];
  __shared__ float psum[4][32], pssq[4][32];
  const int tid = threadIdx.x, lane = tid & 63, wave = tid >> 6;
  const int l15 = lane & 15, quad = lane >> 4;
  const int rowBase = blockIdx.x * 32;

  floatx4 zero = {0.f, 0.f, 0.f, 0.f};
  floatx4 acc[2][8];
#pragma unroll
  for (int mi = 0; mi < 2; mi++)
#pragma unroll
    for (int ni = 0; ni < 8; ni++) acc[mi][ni] = zero;

  for (int k0 = 0; k0 < 512; k0 += 32) {
    __syncthreads();
    if (tid < 128)
      gload_lds16(ctx + (long)(rowBase + (tid >> 2)) * 512 + k0 + ((tid & 3) << 3), &As[tid * 8]);
#pragma unroll
    for (int it = 0; it < 8; it++) {
      int ch = tid + it * 256;
      gload_lds16(Wo + (long)(ch >> 2) * 512 + k0 + ((ch & 3) << 3), &Bs[ch * 8]);
    }
    __syncthreads();
    bf16x8 av[2], bv[8];
#pragma unroll
    for (int mi = 0; mi < 2; mi++)
      av[mi] = *(const bf16x8*)&As[(mi * 16 + l15) * 32 + quad * 8];
#pragma unroll
    for (int ni = 0; ni < 8; ni++)
      bv[ni] = *(const bf16x8*)&Bs[(wave * 128 + ni * 16 + l15) * 32 + quad * 8];
#pragma unroll
    for (int mi = 0; mi < 2; mi++)
#pragma unroll
      for (int ni = 0; ni < 8; ni++)
        acc[mi][ni] = __builtin_amdgcn_mfma_f32_16x16x32_bf16(av[mi], bv[ni], acc[mi][ni], 0, 0, 0);
  }

  float lnw[8], lnb[8], bov[8];
#pragma unroll
  for (int ni = 0; ni < 8; ni++) {
    int col = wave * 128 + ni * 16 + l15;
    bov[ni] = bo[col]; lnw[ni] = w[col]; lnb[ni] = b[col];
  }
#pragma unroll
  for (int mi = 0; mi < 2; mi++) {
#pragma unroll
    for (int r = 0; r < 4; r++) {
      long grow = rowBase + mi * 16 + quad * 4 + r;
      float ps = 0.f, pq = 0.f;
#pragma unroll
      for (int ni = 0; ni < 8; ni++) {
        int col = wave * 128 + ni * 16 + l15;
        float val = acc[mi][ni][r] + bov[ni] + bf2f(h[grow * 512 + col]);
        acc[mi][ni][r] = val;
        ps += val; pq += val * val;
      }
#pragma unroll
      for (int off = 1; off < 16; off <<= 1) { ps += __shfl_xor(ps, off); pq += __shfl_xor(pq, off); }
      if (l15 == 0) { int rl = mi * 16 + quad * 4 + r; psum[wave][rl] = ps; pssq[wave][rl] = pq; }
    }
  }
  __syncthreads();
#pragma unroll
  for (int mi = 0; mi < 2; mi++) {
#pragma unroll
    for (int r = 0; r < 4; r++) {
      int rl = mi * 16 + quad * 4 + r;
      float S = psum[0][rl] + psum[1][rl] + psum[2][rl] + psum[3][rl];
      float Q = pssq[0][rl] + pssq[1][rl] + pssq[2][rl] + pssq[3][rl];
      float mu = S * (1.0f / 512.0f);
      float rstd = rsqrtf(Q * (1.0f / 512.0f) - mu * mu + 1e-5f);
      long grow = rowBase + rl;
#pragma unroll
      for (int ni = 0; ni < 8; ni++) {
        int col = wave * 128 + ni * 16 + l15;
        out[grow * 512 + col] = (acc[mi][ni][r] - mu) * rstd * lnw[ni] + lnb[ni];
      }
    }
  }
}

extern "C" void kernel_launch(void* const* d_in, const int* in_sizes, int n_in,
                              void* d_out, int out_size, void* d_ws, size_t ws_size,
                              hipStream_t stream)
{
  const float* x      = (const float*)d_in[0];
  const float* enc    = (const float*)d_in[1];
  const float* conv_w = (const float*)d_in[2];
  const float* conv_b = (const float*)d_in[3];
  const float* ln1_w  = (const float*)d_in[4];
  const float* ln1_b  = (const float*)d_in[5];
  const float* Wq     = (const float*)d_in[6];
  const float* bq     = (const float*)d_in[7];
  const float* Wk     = (const float*)d_in[8];
  const float* bk     = (const float*)d_in[9];
  const float* Wv     = (const float*)d_in[10];
  const float* bv     = (const float*)d_in[11];
  const float* Wo     = (const float*)d_in[12];
  const float* bo     = (const float*)d_in[13];
  const float* ln2_w  = (const float*)d_in[14];
  const float* ln2_b  = (const float*)d_in[15];

  const long BT = 16384, Dd = 512, S = 2048, TT = 2048;
  float* out  = (float*)d_out;
  float* attn = out + BT * Dd;

  char* p = (char*)d_ws;
  auto alloc = [&](size_t bytes) { char* r = p; p += (bytes + 255) & ~255UL; return r; };
  float*   hglu  = (float*)alloc(BT * Dd * 4);
  ushortT* xpad  = (ushortT*)alloc(8L * 2050 * 512 * 2);
  ushortT* encbf = (ushortT*)alloc(BT * Dd * 2);
  ushortT* hbf   = (ushortT*)alloc(BT * Dd * 2);
  ushortT* qbf   = (ushortT*)alloc(BT * Dd * 2);
  ushortT* kbf   = (ushortT*)alloc(BT * Dd * 2);
  ushortT* vT    = (ushortT*)alloc(Dd * BT * 2);    // [512][16384]
  ushortT* ctxbf = (ushortT*)alloc(BT * Dd * 2);
  ushortT* sl    = (ushortT*)alloc(BT * S * 2);     // logits, then P (bf16)
  ushortT* Wcbf  = (ushortT*)alloc(1024L * 1536 * 2);
  ushortT* wall  = (ushortT*)alloc(4L * 262144 * 2);
  ushortT* Wqbf = wall, *Wkbf = wall + 262144, *Wvbf = wall + 2 * 262144, *Wobf = wall + 3 * 262144;

  // conversions
  k_xpad<<<8 * 2050, 128, 0, stream>>>(x, xpad);
  k_f32_to_bf16v<<<(BT * Dd / 4 + 255) / 256, 256, 0, stream>>>(enc, encbf, BT * Dd / 4);
  k_convw<<<(1024 * 1536 + 255) / 256, 256, 0, stream>>>(conv_w, Wcbf);
  k_w4<<<1024, 256, 0, stream>>>(Wq, Wk, Wv, Wo, wall);

  // conv GEMM + fused GLU + residual -> hglu fp32   (M=16384, N=1024, K=1536)
  k_gemm256<1, 1, 0, 0, 0, 0><<<dim3(64, 4, 1), 512, 0, stream>>>(
      xpad, nullptr, 0, 0, Wcbf, nullptr, 1536, 0,
      conv_b, nullptr, x, hglu, nullptr, nullptr, 0, 512, 1536, 1.0f);
  // LN1 -> hbf bf16
  k_ln<<<16384, 128, 0, stream>>>(hglu, ln1_w, ln1_b, hbf);

  // q = h @ Wq^T + bq  (z=0)  ||  k = enc @ Wk^T + bk  (z=1)  — one 256-block launch
  k_gemm256<0, 0, 1, 1, 1, 0><<<dim3(64, 2, 2), 512, 0, stream>>>(
      hbf, encbf, 512, 0, Wqbf, Wkbf, 512, 0,
      bq, bk, nullptr, nullptr, qbf, kbf, 0, 512, 512, 1.0f);

  // vT = Wv @ enc^T + bv (row bias) -> [512][16384]  (legacy 128² kernel)
  k_gemm<0, 2, 0, 1><<<dim3(4, 128), 256, 0, stream>>>(
      Wvbf, 0, 512, encbf, 0, 512, bv, nullptr, nullptr, vT, 0, 16384, 512, 1.0f);

  // scores -> bf16 logits in sl  (per batch 2048x2048, K=512)
  k_gemm256<0, 0, 0, 1, 0, 0><<<dim3(8, 8, 8), 512, 0, stream>>>(
      qbf, nullptr, 512, TT * Dd, kbf, nullptr, 512, S * Dd,
      nullptr, nullptr, nullptr, nullptr, sl, nullptr,
      TT * S, 2048, 512, 0.04419417382415922f);
  // softmax: sl -> attn fp32 (d_out) + P bf16 in place
  k_softmax<<<16384, 256, 0, stream>>>(sl, attn);

  // ctx = P @ v : A = sl [T,S], B^T = vT; SWAP so consecutive blocks share A panel
  k_gemm256<0, 0, 0, 1, 0, 1><<<dim3(2, 8, 8), 512, 0, stream>>>(
      sl, nullptr, 2048, TT * S, vT, nullptr, 16384, TT,
      nullptr, nullptr, nullptr, nullptr, ctxbf, nullptr,
      TT * Dd, 512, 2048, 1.0f);

  // fused out-proj + residual + LN2 -> out
  k_oproj_ln<<<512, 256, 0, stream>>>(ctxbf, Wobf, bo, hbf, ln2_w, ln2_b, out);
}